// Round 1
// baseline (404.981 us; speedup 1.0000x reference)
//
#include <hip/hip_runtime.h>
#include <hip/hip_bf16.h>
#include <cstdint>
#include <cstddef>

// Problem constants
// B=4, T=256, U=64, H=512, INNER(K)=512, VOCAB(V)=1024
// M = B*T*U = 65536 output rows; out[m][v] = log_softmax over v.

typedef __attribute__((ext_vector_type(8))) short short8;
typedef __attribute__((ext_vector_type(4))) float f32x4;

#define K_DIM 512
#define V_DIM 1024
#define AS_STRIDE 520              // 512 + 8 bf16 pad -> row stride 1040 B (260 dw ≡ 4 mod 32: conflict-free)
#define BS_COL_BYTES 80            // 32 bf16 (64B) + 16B pad -> 20 dw stride: conflict-free
#define BS_BYTES (V_DIM * BS_COL_BYTES)   // 81920 per k-chunk
#define SMEM_BS_OFF (32 * AS_STRIDE * 2)  // 33280
#define SMEM_RED_OFF (SMEM_BS_OFF + BS_BYTES)  // 115200
#define SMEM_TOTAL (SMEM_RED_OFF + 2048)       // + redM[256] + redS[256] floats

// ws layout
#define WS_EP_OFF 0                 // 1024*512 f32 = 2 MiB
#define WS_DP_OFF (1024 * 512 * 4)  // 256*512 f32 = 512 KiB
#define WS_W2_OFF (WS_DP_OFF + 256 * 512 * 4)   // staged W2 bf16: 16*81920 = 1.25 MiB

__device__ __forceinline__ unsigned short f2bf(float x) {
  unsigned int u = __builtin_bit_cast(unsigned int, x);
  u += 0x7FFFu + ((u >> 16) & 1u);   // round-to-nearest-even
  return (unsigned short)(u >> 16);
}

__device__ __forceinline__ float fast_tanh(float x) {
  float ax = fabsf(x);
  float e = __expf(-2.0f * ax);
  float t = (1.0f - e) / (1.0f + e);
  return copysignf(t, x);
}

// ---------------------------------------------------------------------------
// Kernel 1: ep[bt][i] = enc[bt]·W1[:512][i] + b1[i]; dp[bu][i] = dec[bu]·W1[512:][i]
// rows 0..1023 = enc rows, 1024..1279 = dec rows. 8 rows per block.
// ---------------------------------------------------------------------------
__global__ __launch_bounds__(256) void prep_proj(
    const float* __restrict__ enc, const float* __restrict__ dec,
    const float* __restrict__ W1, const float* __restrict__ b1,
    float* __restrict__ ep, float* __restrict__ dp) {
  __shared__ float As[8 * 512];
  const int tid = threadIdx.x;
  const int r0 = blockIdx.x * 8;
  const bool isenc = (r0 < 1024);
  const float* A = isenc ? (enc + (size_t)r0 * 512) : (dec + (size_t)(r0 - 1024) * 512);
  const float* W = isenc ? W1 : (W1 + 512 * 512);
  float* O = isenc ? (ep + (size_t)r0 * 512) : (dp + (size_t)(r0 - 1024) * 512);

  for (int idx = tid; idx < 8 * 512; idx += 256) As[idx] = A[idx];
  __syncthreads();

  const int c0 = tid, c1 = tid + 256;
  float acc0[8], acc1[8];
#pragma unroll
  for (int r = 0; r < 8; ++r) { acc0[r] = 0.0f; acc1[r] = 0.0f; }

  const float4* As4 = (const float4*)As;
  for (int k4 = 0; k4 < 128; ++k4) {
    const int kb = k4 * 4;
    float w00 = W[(size_t)(kb + 0) * 512 + c0];
    float w01 = W[(size_t)(kb + 1) * 512 + c0];
    float w02 = W[(size_t)(kb + 2) * 512 + c0];
    float w03 = W[(size_t)(kb + 3) * 512 + c0];
    float w10 = W[(size_t)(kb + 0) * 512 + c1];
    float w11 = W[(size_t)(kb + 1) * 512 + c1];
    float w12 = W[(size_t)(kb + 2) * 512 + c1];
    float w13 = W[(size_t)(kb + 3) * 512 + c1];
#pragma unroll
    for (int r = 0; r < 8; ++r) {
      float4 a = As4[r * 128 + k4];   // broadcast read (uniform addr): conflict-free
      acc0[r] += a.x * w00 + a.y * w01 + a.z * w02 + a.w * w03;
      acc1[r] += a.x * w10 + a.y * w11 + a.z * w12 + a.w * w13;
    }
  }

  const float bias0 = isenc ? b1[c0] : 0.0f;
  const float bias1 = isenc ? b1[c1] : 0.0f;
#pragma unroll
  for (int r = 0; r < 8; ++r) {
    O[(size_t)r * 512 + c0] = acc0[r] + bias0;
    O[(size_t)r * 512 + c1] = acc1[r] + bias1;
  }
}

// ---------------------------------------------------------------------------
// Kernel 2: repack W2 [512][1024] f32 -> staged bf16 layout:
//   w2st[kc*81920 + v*80 + ki*2] = bf16(W2[kc*32+ki][v]),  kc in 0..15, ki in 0..31
// ---------------------------------------------------------------------------
__global__ __launch_bounds__(256) void prep_w2(const float* __restrict__ W2,
                                               char* __restrict__ w2st) {
  const int v = blockIdx.x * 256 + threadIdx.x;  // 0..1023
  for (int kc = 0; kc < 16; ++kc) {
    unsigned short vals[32];
#pragma unroll
    for (int ki = 0; ki < 32; ++ki)
      vals[ki] = f2bf(W2[(size_t)(kc * 32 + ki) * 1024 + v]);
    uint4* dst = (uint4*)(w2st + (size_t)kc * BS_BYTES + (size_t)v * BS_COL_BYTES);
    const uint4* s = (const uint4*)vals;
    dst[0] = s[0]; dst[1] = s[1]; dst[2] = s[2]; dst[3] = s[3];
  }
}

// ---------------------------------------------------------------------------
// Kernel 3: fused hidden -> GEMM (bf16 MFMA) -> +b2 -> log_softmax -> out
// One block = 32 consecutive output rows (one (b,t), u0..u0+31), full V=1024.
// 512 threads = 8 waves; wave w owns cols [w*128, w*128+128).
// ---------------------------------------------------------------------------
__global__ __launch_bounds__(512, 1) void joint(
    const float* __restrict__ ep, const float* __restrict__ dp,
    const char* __restrict__ w2st, const float* __restrict__ b2,
    float* __restrict__ out) {
  extern __shared__ char smem[];
  unsigned short* As = (unsigned short*)smem;          // [32][520] bf16
  char* Bs = smem + SMEM_BS_OFF;                       // [1024][80B] per k-chunk
  float* redM = (float*)(smem + SMEM_RED_OFF);         // [8 waves][32 rows]
  float* redS = redM + 256;

  const int tid = threadIdx.x;
  const int wave = tid >> 6, lane = tid & 63;
  const int lo = lane & 15, hi = lane >> 4;
  const int m0 = blockIdx.x * 32;
  const int bt = m0 >> 6;                 // b*256 + t
  const int u0 = m0 & 63;                 // 0 or 32
  const int dpbase = ((bt >> 8) << 6) + u0;  // b*64 + u0

  // ---- Phase 1: A-tile hidden[32][512] = tanh(ep + dp) in bf16 ----
  {
    const int c = tid;  // 0..511
    const float e = ep[(size_t)bt * 512 + c];
#pragma unroll 4
    for (int r = 0; r < 32; ++r) {
      float h = fast_tanh(e + dp[(size_t)(dpbase + r) * 512 + c]);
      As[r * AS_STRIDE + c] = f2bf(h);
    }
  }

  f32x4 acc[2][8];
#pragma unroll
  for (int mi = 0; mi < 2; ++mi)
#pragma unroll
    for (int ni = 0; ni < 8; ++ni)
#pragma unroll
      for (int j = 0; j < 4; ++j) acc[mi][ni][j] = 0.0f;

  const int nbase = wave * 128;

  // ---- Phase 2: K loop, BK=32 per step ----
  for (int kc = 0; kc < 16; ++kc) {
    __syncthreads();  // previous compute done (also covers Phase-1 As writes at kc=0)
    const char* src = w2st + (size_t)kc * BS_BYTES;
#pragma unroll
    for (int r = 0; r < 10; ++r) {        // 81920 B / (512 thr * 16 B)
      const int off = (r * 512 + tid) * 16;
      *(uint4*)(Bs + off) = *(const uint4*)(src + off);
    }
    __syncthreads();

    short8 a0 = *(const short8*)(smem + ((size_t)lo * AS_STRIDE + kc * 32 + hi * 8) * 2);
    short8 a1 = *(const short8*)(smem + ((size_t)(16 + lo) * AS_STRIDE + kc * 32 + hi * 8) * 2);
#pragma unroll
    for (int ni = 0; ni < 8; ++ni) {
      short8 b = *(const short8*)(Bs + (size_t)(nbase + ni * 16 + lo) * BS_COL_BYTES + hi * 16);
      acc[0][ni] = __builtin_amdgcn_mfma_f32_16x16x32_bf16(a0, b, acc[0][ni], 0, 0, 0);
      acc[1][ni] = __builtin_amdgcn_mfma_f32_16x16x32_bf16(a1, b, acc[1][ni], 0, 0, 0);
    }
  }
  __syncthreads();

  // ---- Phase 3: +b2, log_softmax over V (cross-lane + cross-wave) ----
  float b2v[8];
#pragma unroll
  for (int ni = 0; ni < 8; ++ni) b2v[ni] = b2[nbase + ni * 16 + lo];
#pragma unroll
  for (int mi = 0; mi < 2; ++mi)
#pragma unroll
    for (int ni = 0; ni < 8; ++ni)
#pragma unroll
      for (int j = 0; j < 4; ++j) acc[mi][ni][j] += b2v[ni];

  // per-thread partial max over its 8 cols, per held row
  float pm[2][4];
#pragma unroll
  for (int mi = 0; mi < 2; ++mi)
#pragma unroll
    for (int r = 0; r < 4; ++r) {
      float m = -3.402823e38f;
#pragma unroll
      for (int ni = 0; ni < 8; ++ni) m = fmaxf(m, acc[mi][ni][r]);
      pm[mi][r] = m;
    }
  // reduce across the 16 lanes sharing each row (xor over low 4 lane bits)
#pragma unroll
  for (int off = 1; off < 16; off <<= 1)
#pragma unroll
    for (int mi = 0; mi < 2; ++mi)
#pragma unroll
      for (int r = 0; r < 4; ++r)
        pm[mi][r] = fmaxf(pm[mi][r], __shfl_xor(pm[mi][r], off));
  if (lo == 0) {
#pragma unroll
    for (int mi = 0; mi < 2; ++mi)
#pragma unroll
      for (int r = 0; r < 4; ++r)
        redM[wave * 32 + mi * 16 + hi * 4 + r] = pm[mi][r];
  }
  __syncthreads();
  float rm[2][4];
#pragma unroll
  for (int mi = 0; mi < 2; ++mi)
#pragma unroll
    for (int r = 0; r < 4; ++r) {
      const int row = mi * 16 + hi * 4 + r;
      float m = redM[row];
#pragma unroll
      for (int w = 1; w < 8; ++w) m = fmaxf(m, redM[w * 32 + row]);
      rm[mi][r] = m;
    }

  float ps[2][4];
#pragma unroll
  for (int mi = 0; mi < 2; ++mi)
#pragma unroll
    for (int r = 0; r < 4; ++r) {
      float s = 0.0f;
#pragma unroll
      for (int ni = 0; ni < 8; ++ni) s += __expf(acc[mi][ni][r] - rm[mi][r]);
      ps[mi][r] = s;
    }
#pragma unroll
  for (int off = 1; off < 16; off <<= 1)
#pragma unroll
    for (int mi = 0; mi < 2; ++mi)
#pragma unroll
      for (int r = 0; r < 4; ++r)
        ps[mi][r] += __shfl_xor(ps[mi][r], off);
  if (lo == 0) {
#pragma unroll
    for (int mi = 0; mi < 2; ++mi)
#pragma unroll
      for (int r = 0; r < 4; ++r)
        redS[wave * 32 + mi * 16 + hi * 4 + r] = ps[mi][r];
  }
  __syncthreads();

#pragma unroll
  for (int mi = 0; mi < 2; ++mi)
#pragma unroll
    for (int r = 0; r < 4; ++r) {
      const int row = mi * 16 + hi * 4 + r;
      float s = 0.0f;
#pragma unroll
      for (int w = 0; w < 8; ++w) s += redS[w * 32 + row];
      const float sub = rm[mi][r] + __logf(s);
      float* op = out + (size_t)(m0 + row) * 1024 + nbase + lo;
#pragma unroll
      for (int ni = 0; ni < 8; ++ni) op[ni * 16] = acc[mi][ni][r] - sub;
    }
}

// ---------------------------------------------------------------------------
extern "C" void kernel_launch(void* const* d_in, const int* in_sizes, int n_in,
                              void* d_out, int out_size, void* d_ws, size_t ws_size,
                              hipStream_t stream) {
  const float* enc = (const float*)d_in[0];  // [4,256,512]
  const float* dec = (const float*)d_in[1];  // [4,64,512]
  const float* W1  = (const float*)d_in[2];  // [1024,512]
  const float* b1  = (const float*)d_in[3];  // [512]
  const float* W2  = (const float*)d_in[4];  // [512,1024]
  const float* b2  = (const float*)d_in[5];  // [1024]
  float* out = (float*)d_out;                // [65536,1024] f32

  char* ws = (char*)d_ws;
  float* ep = (float*)(ws + WS_EP_OFF);
  float* dp = (float*)(ws + WS_DP_OFF);
  char* w2st = ws + WS_W2_OFF;

  prep_proj<<<160, 256, 0, stream>>>(enc, dec, W1, b1, ep, dp);
  prep_w2<<<4, 256, 0, stream>>>(W2, w2st);
  joint<<<2048, 512, SMEM_TOTAL, stream>>>(ep, dp, w2st, b2, out);
}

// Round 2
// 215.092 us; speedup vs baseline: 1.8828x; 1.8828x over previous
//
#include <hip/hip_runtime.h>
#include <hip/hip_bf16.h>
#include <cstdint>
#include <cstddef>

// B=4, T=256, U=64, H=512, K=512, V=1024; M = 65536 rows, log_softmax over V.

typedef __attribute__((ext_vector_type(8))) short short8;
typedef __attribute__((ext_vector_type(4))) float f32x4;

#define AS_STRIDE 520                       // 512 + 8 bf16 pad (row stride 1040 B)
#define SMEM_A_BYTES (64 * AS_STRIDE * 2)   // 66560
#define SMEM_BS_OFF SMEM_A_BYTES
#define BS_CHUNK 65536                      // 1024 cols * 32k * 2B, unpadded (gload_lds needs linear)
#define SMEM_RED_OFF (SMEM_BS_OFF + BS_CHUNK)      // 132096
#define SMEM_TOTAL (SMEM_RED_OFF + 16 * 64 * 4 * 2) // +8 KB redM/redS = 140288 (< 160 KiB)

// ws layout
#define WS_EP_OFF 0                           // 1024*512 f32 = 2 MiB
#define WS_DP_OFF (1024 * 512 * 4)            // 256*512 f32 = 512 KiB
#define WS_W2_OFF (WS_DP_OFF + 256 * 512 * 4) // staged W2 bf16: 16 chunks * 64 KiB = 1 MiB

__device__ __forceinline__ unsigned short f2bf(float x) {
  unsigned int u = __builtin_bit_cast(unsigned int, x);
  u += 0x7FFFu + ((u >> 16) & 1u);
  return (unsigned short)(u >> 16);
}

__device__ __forceinline__ float fast_tanh(float x) {
  float ax = fabsf(x);
  float e = __expf(-2.0f * ax);
  float t = (1.0f - e) / (1.0f + e);
  return copysignf(t, x);
}

__device__ __forceinline__ void gload_lds16(const void* g, void* l) {
  __builtin_amdgcn_global_load_lds(
      (const __attribute__((address_space(1))) unsigned int*)g,
      (__attribute__((address_space(3))) unsigned int*)l, 16, 0, 0);
}

// ---------------------------------------------------------------------------
// prep_proj: 4 rows per block, 512 threads (8 waves), 320 blocks.
// rows 0..1023 = enc -> ep (+b1), rows 1024..1279 = dec -> dp.
// ---------------------------------------------------------------------------
__global__ __launch_bounds__(512) void prep_proj(
    const float* __restrict__ enc, const float* __restrict__ dec,
    const float* __restrict__ W1, const float* __restrict__ b1,
    float* __restrict__ ep, float* __restrict__ dp) {
  __shared__ float As[4 * 512];
  const int tid = threadIdx.x;
  const int r0 = blockIdx.x * 4;
  const bool isenc = (r0 < 1024);
  const float* A = isenc ? (enc + (size_t)r0 * 512) : (dec + (size_t)(r0 - 1024) * 512);
  const float* W = isenc ? W1 : (W1 + 512 * 512);
  float* O = isenc ? (ep + (size_t)r0 * 512) : (dp + (size_t)(r0 - 1024) * 512);

  for (int idx = tid; idx < 4 * 512; idx += 512) As[idx] = A[idx];
  __syncthreads();

  const int c = tid;
  float acc[4] = {0.f, 0.f, 0.f, 0.f};
  const float4* As4 = (const float4*)As;
#pragma unroll 4
  for (int k4 = 0; k4 < 128; ++k4) {
    const int kb = k4 * 4;
    float w0 = W[(size_t)(kb + 0) * 512 + c];
    float w1 = W[(size_t)(kb + 1) * 512 + c];
    float w2 = W[(size_t)(kb + 2) * 512 + c];
    float w3 = W[(size_t)(kb + 3) * 512 + c];
#pragma unroll
    for (int r = 0; r < 4; ++r) {
      float4 a = As4[r * 128 + k4];  // uniform addr -> broadcast, conflict-free
      acc[r] += a.x * w0 + a.y * w1 + a.z * w2 + a.w * w3;
    }
  }
  const float bias = isenc ? b1[c] : 0.0f;
#pragma unroll
  for (int r = 0; r < 4; ++r) O[(size_t)r * 512 + c] = acc[r] + bias;
}

// ---------------------------------------------------------------------------
// prep_w2: repack W2 [512][1024] f32 -> bf16 staged image matching LDS layout:
//   w2st[kc*65536 + v*64 + ki*2] = bf16(W2[kc*32+ki][v])
// 64 blocks x 256 threads: one (kc, v) pair per thread.
// ---------------------------------------------------------------------------
__global__ __launch_bounds__(256) void prep_w2(const float* __restrict__ W2,
                                               char* __restrict__ w2st) {
  const int g = blockIdx.x * 256 + threadIdx.x;  // 0..16383
  const int v = g & 1023;
  const int kc = g >> 10;
  unsigned short vals[32];
#pragma unroll
  for (int ki = 0; ki < 32; ++ki)
    vals[ki] = f2bf(W2[(size_t)(kc * 32 + ki) * 1024 + v]);
  uint4* dst = (uint4*)(w2st + (size_t)kc * BS_CHUNK + (size_t)v * 64);
  const uint4* s = (const uint4*)vals;
  dst[0] = s[0]; dst[1] = s[1]; dst[2] = s[2]; dst[3] = s[3];
}

// ---------------------------------------------------------------------------
// joint: one block = 64 rows (one (b,t), all u) x full V=1024.
// 1024 threads = 16 waves, 2M x 8N: wave (wm,wn) owns rows wm*32+0..31,
// cols wn*128..+127. B staged per BK=32 chunk via global_load_lds.
// ---------------------------------------------------------------------------
__global__ __launch_bounds__(1024, 1) void joint(
    const float* __restrict__ ep, const float* __restrict__ dp,
    const char* __restrict__ w2st, const float* __restrict__ b2,
    float* __restrict__ out) {
  extern __shared__ char smem[];
  unsigned short* As = (unsigned short*)smem;      // [64][520] bf16
  char* Bs = smem + SMEM_BS_OFF;                   // [1024 cols][64 B] per chunk
  float* redM = (float*)(smem + SMEM_RED_OFF);     // [16 waves][64 rows]
  float* redS = redM + 16 * 64;

  const int tid = threadIdx.x;
  const int wave = tid >> 6, lane = tid & 63;
  const int lo = lane & 15, hi = lane >> 4;
  const int wm = wave >> 3, wn = wave & 7;
  const int bt = blockIdx.x;            // 0..1023
  const int m0 = bt * 64;
  const int dpbase = (bt >> 8) * 64;    // b*64

  // -- prologue: issue stage of chunk 0 (overlaps with tanh phase) --
  {
    const char* src = w2st;
#pragma unroll
    for (int r = 0; r < 4; ++r) {
      const int off = r * 16384 + tid * 16;
      gload_lds16(src + off, Bs + off);
    }
  }

  // -- phase 1: A-tile hidden[64][512] = tanh(ep + dp) -> bf16 LDS --
  {
    const int c = tid & 511;
    const int rh = tid >> 9;            // row half: 0 or 1
    const float e = ep[(size_t)bt * 512 + c];
#pragma unroll 4
    for (int r = 0; r < 32; ++r) {
      const int row = rh * 32 + r;
      float h = fast_tanh(e + dp[(size_t)(dpbase + row) * 512 + c]);
      As[row * AS_STRIDE + c] = f2bf(h);
    }
  }

  f32x4 acc[2][8];
#pragma unroll
  for (int mi = 0; mi < 2; ++mi)
#pragma unroll
    for (int ni = 0; ni < 8; ++ni)
#pragma unroll
      for (int j = 0; j < 4; ++j) acc[mi][ni][j] = 0.0f;

  const int nbase = wn * 128;
  const int arow0 = wm * 32 + lo;

  // -- K loop: 16 chunks of BK=32, single-buffer, m97-style 2-barrier --
  for (int kc = 0; kc < 16; ++kc) {
    __syncthreads();   // stage(kc) drained (vmcnt0 before barrier); As visible at kc=0
    short8 a0 = *(const short8*)(As + (size_t)arow0 * AS_STRIDE + kc * 32 + hi * 8);
    short8 a1 = *(const short8*)(As + (size_t)(arow0 + 16) * AS_STRIDE + kc * 32 + hi * 8);
#pragma unroll
    for (int ni = 0; ni < 8; ++ni) {
      short8 b = *(const short8*)(Bs + (size_t)(nbase + ni * 16 + lo) * 64 + hi * 16);
      acc[0][ni] = __builtin_amdgcn_mfma_f32_16x16x32_bf16(a0, b, acc[0][ni], 0, 0, 0);
      acc[1][ni] = __builtin_amdgcn_mfma_f32_16x16x32_bf16(a1, b, acc[1][ni], 0, 0, 0);
    }
    if (kc < 15) {
      __syncthreads();   // all waves done reading Bs
      const char* src = w2st + (size_t)(kc + 1) * BS_CHUNK;
#pragma unroll
      for (int r = 0; r < 4; ++r) {
        const int off = r * 16384 + tid * 16;
        gload_lds16(src + off, Bs + off);
      }
    }
  }
  __syncthreads();

  // -- phase 3: +b2, log_softmax, store --
  float b2v[8];
#pragma unroll
  for (int ni = 0; ni < 8; ++ni) b2v[ni] = b2[nbase + ni * 16 + lo];
#pragma unroll
  for (int mi = 0; mi < 2; ++mi)
#pragma unroll
    for (int ni = 0; ni < 8; ++ni)
#pragma unroll
      for (int j = 0; j < 4; ++j) acc[mi][ni][j] += b2v[ni];

  // per-thread max over 8 cols per held row
  float pm[2][4];
#pragma unroll
  for (int mi = 0; mi < 2; ++mi)
#pragma unroll
    for (int r = 0; r < 4; ++r) {
      float m = -3.402823e38f;
#pragma unroll
      for (int ni = 0; ni < 8; ++ni) m = fmaxf(m, acc[mi][ni][r]);
      pm[mi][r] = m;
    }
#pragma unroll
  for (int off = 1; off < 16; off <<= 1)
#pragma unroll
    for (int mi = 0; mi < 2; ++mi)
#pragma unroll
      for (int r = 0; r < 4; ++r)
        pm[mi][r] = fmaxf(pm[mi][r], __shfl_xor(pm[mi][r], off));
  if (lo == 0) {
#pragma unroll
    for (int mi = 0; mi < 2; ++mi)
#pragma unroll
      for (int r = 0; r < 4; ++r)
        redM[wave * 64 + wm * 32 + mi * 16 + hi * 4 + r] = pm[mi][r];
  }
  __syncthreads();
  float rm[2][4];
#pragma unroll
  for (int mi = 0; mi < 2; ++mi)
#pragma unroll
    for (int r = 0; r < 4; ++r) {
      const int gr = wm * 32 + mi * 16 + hi * 4 + r;
      float m = redM[(wm * 8 + 0) * 64 + gr];
#pragma unroll
      for (int w = 1; w < 8; ++w) m = fmaxf(m, redM[(wm * 8 + w) * 64 + gr]);
      rm[mi][r] = m;
    }

  float ps[2][4];
#pragma unroll
  for (int mi = 0; mi < 2; ++mi)
#pragma unroll
    for (int r = 0; r < 4; ++r) {
      float s = 0.0f;
#pragma unroll
      for (int ni = 0; ni < 8; ++ni) s += __expf(acc[mi][ni][r] - rm[mi][r]);
      ps[mi][r] = s;
    }
#pragma unroll
  for (int off = 1; off < 16; off <<= 1)
#pragma unroll
    for (int mi = 0; mi < 2; ++mi)
#pragma unroll
      for (int r = 0; r < 4; ++r)
        ps[mi][r] += __shfl_xor(ps[mi][r], off);
  if (lo == 0) {
#pragma unroll
    for (int mi = 0; mi < 2; ++mi)
#pragma unroll
      for (int r = 0; r < 4; ++r)
        redS[wave * 64 + wm * 32 + mi * 16 + hi * 4 + r] = ps[mi][r];
  }
  __syncthreads();

#pragma unroll
  for (int mi = 0; mi < 2; ++mi)
#pragma unroll
    for (int r = 0; r < 4; ++r) {
      const int gr = wm * 32 + mi * 16 + hi * 4 + r;
      float s = 0.0f;
#pragma unroll
      for (int w = 0; w < 8; ++w) s += redS[(wm * 8 + w) * 64 + gr];
      const float sub = rm[mi][r] + __logf(s);
      float* op = out + (size_t)(m0 + gr) * 1024 + nbase + lo;
#pragma unroll
      for (int ni = 0; ni < 8; ++ni) op[ni * 16] = acc[mi][ni][r] - sub;
    }
}

// ---------------------------------------------------------------------------
extern "C" void kernel_launch(void* const* d_in, const int* in_sizes, int n_in,
                              void* d_out, int out_size, void* d_ws, size_t ws_size,
                              hipStream_t stream) {
  const float* enc = (const float*)d_in[0];
  const float* dec = (const float*)d_in[1];
  const float* W1  = (const float*)d_in[2];
  const float* b1  = (const float*)d_in[3];
  const float* W2  = (const float*)d_in[4];
  const float* b2  = (const float*)d_in[5];
  float* out = (float*)d_out;

  char* ws = (char*)d_ws;
  float* ep = (float*)(ws + WS_EP_OFF);
  float* dp = (float*)(ws + WS_DP_OFF);
  char* w2st = ws + WS_W2_OFF;

  prep_proj<<<320, 512, 0, stream>>>(enc, dec, W1, b1, ep, dp);
  prep_w2<<<64, 256, 0, stream>>>(W2, w2st);
  joint<<<1024, 1024, SMEM_TOTAL, stream>>>(ep, dp, w2st, b2, out);
}

// Round 3
// 198.560 us; speedup vs baseline: 2.0396x; 1.0833x over previous
//
#include <hip/hip_runtime.h>
#include <hip/hip_bf16.h>
#include <cstdint>
#include <cstddef>

// B=4, T=256, U=64, H=512, K=512, V=1024; M = 65536 rows, log_softmax over V.

typedef __attribute__((ext_vector_type(8))) short short8;
typedef __attribute__((ext_vector_type(4))) float f32x4;

#define AS_STRIDE 520                       // 512 + 8 bf16 pad (row stride 1040 B)
#define SMEM_A_BYTES (64 * AS_STRIDE * 2)   // 66560
#define SMEM_BS_OFF SMEM_A_BYTES
#define BS_CHUNK 65536                      // 1024 cols * 32k * 2B
#define SMEM_RED_OFF (SMEM_BS_OFF + BS_CHUNK)        // 132096
#define SMEM_TOTAL (SMEM_RED_OFF + 16 * 64 * 4 * 2)  // 140288 (< 160 KiB)

// ws layout
#define WS_EP_OFF 0                           // 1024*512 f32 = 2 MiB
#define WS_DP_OFF (1024 * 512 * 4)            // 256*512 f32 = 512 KiB
#define WS_W2_OFF (WS_DP_OFF + 256 * 512 * 4) // staged W2 bf16: 16 chunks * 64 KiB

__device__ __forceinline__ unsigned short f2bf(float x) {
  unsigned int u = __builtin_bit_cast(unsigned int, x);
  u += 0x7FFFu + ((u >> 16) & 1u);
  return (unsigned short)(u >> 16);
}

__device__ __forceinline__ float fast_tanh(float x) {
  float ax = fabsf(x);
  float e = __expf(-2.0f * ax);
  float t = (1.0f - e) / (1.0f + e);
  return copysignf(t, x);
}

// ---------------------------------------------------------------------------
// prep (fused): blocks 0..319 -> projections (4 rows each);
//               blocks 320..351 -> W2 repack to bf16 staged image.
// ---------------------------------------------------------------------------
__global__ __launch_bounds__(512) void prep(
    const float* __restrict__ enc, const float* __restrict__ dec,
    const float* __restrict__ W1, const float* __restrict__ b1,
    const float* __restrict__ W2,
    float* __restrict__ ep, float* __restrict__ dp, char* __restrict__ w2st) {
  __shared__ float As[4 * 512];
  const int tid = threadIdx.x;
  if (blockIdx.x < 320) {
    const int r0 = blockIdx.x * 4;
    const bool isenc = (r0 < 1024);
    const float* A = isenc ? (enc + (size_t)r0 * 512) : (dec + (size_t)(r0 - 1024) * 512);
    const float* W = isenc ? W1 : (W1 + 512 * 512);
    float* O = isenc ? (ep + (size_t)r0 * 512) : (dp + (size_t)(r0 - 1024) * 512);

    for (int idx = tid; idx < 4 * 512; idx += 512) As[idx] = A[idx];
    __syncthreads();

    const int c = tid;
    float acc[4] = {0.f, 0.f, 0.f, 0.f};
    const float4* As4 = (const float4*)As;
#pragma unroll 4
    for (int k4 = 0; k4 < 128; ++k4) {
      const int kb = k4 * 4;
      float w0 = W[(size_t)(kb + 0) * 512 + c];
      float w1 = W[(size_t)(kb + 1) * 512 + c];
      float w2 = W[(size_t)(kb + 2) * 512 + c];
      float w3 = W[(size_t)(kb + 3) * 512 + c];
#pragma unroll
      for (int r = 0; r < 4; ++r) {
        float4 a = As4[r * 128 + k4];
        acc[r] += a.x * w0 + a.y * w1 + a.z * w2 + a.w * w3;
      }
    }
    const float bias = isenc ? b1[c] : 0.0f;
#pragma unroll
    for (int r = 0; r < 4; ++r) O[(size_t)r * 512 + c] = acc[r] + bias;
  } else {
    const int g = (blockIdx.x - 320) * 512 + tid;  // 0..16383
    const int v = g & 1023;
    const int kc = g >> 10;
    unsigned short vals[32];
#pragma unroll
    for (int ki = 0; ki < 32; ++ki)
      vals[ki] = f2bf(W2[(size_t)(kc * 32 + ki) * 1024 + v]);
    uint4* dst = (uint4*)(w2st + (size_t)kc * BS_CHUNK + (size_t)v * 64);
    const uint4* s = (const uint4*)vals;
    dst[0] = s[0]; dst[1] = s[1]; dst[2] = s[2]; dst[3] = s[3];
  }
}

// ---------------------------------------------------------------------------
// joint: block = 64 rows (one (b,t)) x V=1024; 1024 threads = 16 waves (2Mx8N).
// B staged per BK=32 chunk via register-staged depth-2 pipeline:
//   regs P = chunk kc, Q = chunk kc+1 in flight; single LDS B buffer.
//   raw s_barrier + compiler-counted vmcnt (NO __syncthreads in K-loop).
// ---------------------------------------------------------------------------
__global__ __launch_bounds__(1024, 1) void joint(
    const float* __restrict__ ep, const float* __restrict__ dp,
    const char* __restrict__ w2st, const float* __restrict__ b2,
    float* __restrict__ out) {
  extern __shared__ char smem[];
  unsigned short* As = (unsigned short*)smem;      // [64][520] bf16
  char* Bs = smem + SMEM_BS_OFF;                   // [1024 cols][64 B] one chunk
  float* redM = (float*)(smem + SMEM_RED_OFF);
  float* redS = redM + 16 * 64;

  const int tid = threadIdx.x;
  const int wave = tid >> 6, lane = tid & 63;
  const int lo = lane & 15, hi = lane >> 4;
  const int wm = wave >> 3, wn = wave & 7;
  const int bt = blockIdx.x;
  const int m0 = bt * 64;
  const int dpbase = (bt >> 8) * 64;

  // -- prologue: prefetch chunks 0 and 1 into register sets P, Q --
  uint4 P0, P1, P2, P3, Q0, Q1, Q2, Q3;
  {
    const char* s0 = w2st;
    const char* s1 = w2st + BS_CHUNK;
    P0 = *(const uint4*)(s0 + 0 * 16384 + tid * 16);
    P1 = *(const uint4*)(s0 + 1 * 16384 + tid * 16);
    P2 = *(const uint4*)(s0 + 2 * 16384 + tid * 16);
    P3 = *(const uint4*)(s0 + 3 * 16384 + tid * 16);
    Q0 = *(const uint4*)(s1 + 0 * 16384 + tid * 16);
    Q1 = *(const uint4*)(s1 + 1 * 16384 + tid * 16);
    Q2 = *(const uint4*)(s1 + 2 * 16384 + tid * 16);
    Q3 = *(const uint4*)(s1 + 3 * 16384 + tid * 16);
  }

  // -- phase 1: A-tile hidden[64][512] = tanh(ep + dp) -> bf16 LDS --
  {
    const int c = tid & 511;
    const int rh = tid >> 9;
    const float e = ep[(size_t)bt * 512 + c];
#pragma unroll 4
    for (int r = 0; r < 32; ++r) {
      const int row = rh * 32 + r;
      float h = fast_tanh(e + dp[(size_t)(dpbase + row) * 512 + c]);
      As[row * AS_STRIDE + c] = f2bf(h);
    }
  }

  f32x4 acc[2][8];
#pragma unroll
  for (int mi = 0; mi < 2; ++mi)
#pragma unroll
    for (int ni = 0; ni < 8; ++ni)
#pragma unroll
      for (int j = 0; j < 4; ++j) acc[mi][ni][j] = 0.0f;

  const int nbase = wn * 128;
  const int arow0 = wm * 32 + lo;

  __syncthreads();  // A visible to all; prologue loads also landed (drain is fine here)

  // One pipeline step: write SET -> Bs, optionally prefetch NEXT into SET,
  // make writes visible, then 16 MFMA on chunk KC.
#define K_STEP(S0, S1, S2, S3, KC, PF, NEXT)                                        \
  {                                                                                 \
    __builtin_amdgcn_s_barrier();    /* all waves done reading Bs(prev) */          \
    asm volatile("" ::: "memory");                                                  \
    *(uint4*)(Bs + 0 * 16384 + tid * 16) = S0;  /* compiler adds counted vmcnt */   \
    *(uint4*)(Bs + 1 * 16384 + tid * 16) = S1;                                      \
    *(uint4*)(Bs + 2 * 16384 + tid * 16) = S2;                                      \
    *(uint4*)(Bs + 3 * 16384 + tid * 16) = S3;                                      \
    if (PF) {                                                                       \
      const char* _src = w2st + (size_t)(NEXT)*BS_CHUNK;                            \
      S0 = *(const uint4*)(_src + 0 * 16384 + tid * 16);                            \
      S1 = *(const uint4*)(_src + 1 * 16384 + tid * 16);                            \
      S2 = *(const uint4*)(_src + 2 * 16384 + tid * 16);                            \
      S3 = *(const uint4*)(_src + 3 * 16384 + tid * 16);                            \
    }                                                                               \
    asm volatile("s_waitcnt lgkmcnt(0)" ::: "memory"); /* my ds_writes committed */ \
    __builtin_amdgcn_s_barrier();    /* everyone's writes visible */                \
    asm volatile("" ::: "memory");                                                  \
    __builtin_amdgcn_sched_barrier(0);                                              \
    short8 a0 = *(const short8*)(As + (size_t)arow0 * AS_STRIDE + (KC)*32 + hi * 8);\
    short8 a1 = *(const short8*)(As + (size_t)(arow0 + 16) * AS_STRIDE + (KC)*32 + hi * 8); \
    __builtin_amdgcn_s_setprio(1);                                                  \
    _Pragma("unroll")                                                               \
    for (int ni = 0; ni < 8; ++ni) {                                                \
      short8 b = *(const short8*)(Bs + (size_t)(nbase + ni * 16 + lo) * 64 + hi * 16); \
      acc[0][ni] = __builtin_amdgcn_mfma_f32_16x16x32_bf16(a0, b, acc[0][ni], 0, 0, 0); \
      acc[1][ni] = __builtin_amdgcn_mfma_f32_16x16x32_bf16(a1, b, acc[1][ni], 0, 0, 0); \
    }                                                                               \
    __builtin_amdgcn_s_setprio(0);                                                  \
  }

  // kc = 0..13: prefetch kc+2; kc = 14,15: no prefetch.
  for (int kc2 = 0; kc2 < 7; ++kc2) {
    const int kc = kc2 * 2;
    K_STEP(P0, P1, P2, P3, kc, 1, kc + 2);
    K_STEP(Q0, Q1, Q2, Q3, kc + 1, 1, kc + 3);
  }
  K_STEP(P0, P1, P2, P3, 14, 0, 0);
  K_STEP(Q0, Q1, Q2, Q3, 15, 0, 0);
#undef K_STEP

  __syncthreads();

  // -- phase 3: +b2, log_softmax, store --
  float b2v[8];
#pragma unroll
  for (int ni = 0; ni < 8; ++ni) b2v[ni] = b2[nbase + ni * 16 + lo];
#pragma unroll
  for (int mi = 0; mi < 2; ++mi)
#pragma unroll
    for (int ni = 0; ni < 8; ++ni)
#pragma unroll
      for (int j = 0; j < 4; ++j) acc[mi][ni][j] += b2v[ni];

  float pm[2][4];
#pragma unroll
  for (int mi = 0; mi < 2; ++mi)
#pragma unroll
    for (int r = 0; r < 4; ++r) {
      float m = -3.402823e38f;
#pragma unroll
      for (int ni = 0; ni < 8; ++ni) m = fmaxf(m, acc[mi][ni][r]);
      pm[mi][r] = m;
    }
#pragma unroll
  for (int off = 1; off < 16; off <<= 1)
#pragma unroll
    for (int mi = 0; mi < 2; ++mi)
#pragma unroll
      for (int r = 0; r < 4; ++r)
        pm[mi][r] = fmaxf(pm[mi][r], __shfl_xor(pm[mi][r], off));
  if (lo == 0) {
#pragma unroll
    for (int mi = 0; mi < 2; ++mi)
#pragma unroll
      for (int r = 0; r < 4; ++r)
        redM[wave * 64 + wm * 32 + mi * 16 + hi * 4 + r] = pm[mi][r];
  }
  __syncthreads();
  float rm[2][4];
#pragma unroll
  for (int mi = 0; mi < 2; ++mi)
#pragma unroll
    for (int r = 0; r < 4; ++r) {
      const int gr = wm * 32 + mi * 16 + hi * 4 + r;
      float m = redM[(wm * 8 + 0) * 64 + gr];
#pragma unroll
      for (int w = 1; w < 8; ++w) m = fmaxf(m, redM[(wm * 8 + w) * 64 + gr]);
      rm[mi][r] = m;
    }

  float ps[2][4];
#pragma unroll
  for (int mi = 0; mi < 2; ++mi)
#pragma unroll
    for (int r = 0; r < 4; ++r) {
      float s = 0.0f;
#pragma unroll
      for (int ni = 0; ni < 8; ++ni) s += __expf(acc[mi][ni][r] - rm[mi][r]);
      ps[mi][r] = s;
    }
#pragma unroll
  for (int off = 1; off < 16; off <<= 1)
#pragma unroll
    for (int mi = 0; mi < 2; ++mi)
#pragma unroll
      for (int r = 0; r < 4; ++r)
        ps[mi][r] += __shfl_xor(ps[mi][r], off);
  if (lo == 0) {
#pragma unroll
    for (int mi = 0; mi < 2; ++mi)
#pragma unroll
      for (int r = 0; r < 4; ++r)
        redS[wave * 64 + wm * 32 + mi * 16 + hi * 4 + r] = ps[mi][r];
  }
  __syncthreads();

#pragma unroll
  for (int mi = 0; mi < 2; ++mi)
#pragma unroll
    for (int r = 0; r < 4; ++r) {
      const int gr = wm * 32 + mi * 16 + hi * 4 + r;
      float s = 0.0f;
#pragma unroll
      for (int w = 0; w < 8; ++w) s += redS[(wm * 8 + w) * 64 + gr];
      const float sub = rm[mi][r] + __logf(s);
      float* op = out + (size_t)(m0 + gr) * 1024 + nbase + lo;
#pragma unroll
      for (int ni = 0; ni < 8; ++ni) op[ni * 16] = acc[mi][ni][r] - sub;
    }
}

// ---------------------------------------------------------------------------
extern "C" void kernel_launch(void* const* d_in, const int* in_sizes, int n_in,
                              void* d_out, int out_size, void* d_ws, size_t ws_size,
                              hipStream_t stream) {
  const float* enc = (const float*)d_in[0];
  const float* dec = (const float*)d_in[1];
  const float* W1  = (const float*)d_in[2];
  const float* b1  = (const float*)d_in[3];
  const float* W2  = (const float*)d_in[4];
  const float* b2  = (const float*)d_in[5];
  float* out = (float*)d_out;

  char* ws = (char*)d_ws;
  float* ep = (float*)(ws + WS_EP_OFF);
  float* dp = (float*)(ws + WS_DP_OFF);
  char* w2st = ws + WS_W2_OFF;

  prep<<<352, 512, 0, stream>>>(enc, dec, W1, b1, W2, ep, dp, w2st);
  joint<<<1024, 1024, SMEM_TOTAL, stream>>>(ep, dp, w2st, b2, out);
}